// Round 8
// baseline (190.968 us; speedup 1.0000x reference)
//
#include <hip/hip_runtime.h>

#define NUM 2560
#define DIM 128
#define NTOT 65536          // 16*64*64 rows
#define CHUNK 64            // codes per chunk
#define NCH 40              // 2560 / 64

typedef _Float16 f16;
typedef _Float16 f16x4 __attribute__((ext_vector_type(4)));
typedef _Float16 f16x8 __attribute__((ext_vector_type(8)));
typedef float    f32x4 __attribute__((ext_vector_type(4)));

__device__ __forceinline__ unsigned int ford(float f) {
    unsigned int u = __float_as_uint(f);
    return ((int)u < 0) ? ~u : (u | 0x80000000u);
}

__device__ __forceinline__ void load_lds16(const void* g, void* l) {
    __builtin_amdgcn_global_load_lds(
        (const __attribute__((address_space(1))) void*)g,
        (__attribute__((address_space(3))) void*)l, 16, 0, 0);
}

// ---------------- prep: pre-swizzled fp16 codebook image ----------------
// 40 chunks x 16KB; chunk-row jl (64), granule g (16, k=8g..8g+7):
// byte = chunk*16384 + (jl<<8) + ((g ^ (jl&7))<<4)
__global__ __launch_bounds__(256) void prep_code(const float* __restrict__ w,
                                                 f16* __restrict__ bp) {
    int T = blockIdx.x * 256 + threadIdx.x;       // 0..40959
    if (T >= NUM * 16) return;
    int g = T & 15, j = T >> 4;
    int chunk = j >> 6, jl = j & 63;
    const float* src = w + (size_t)j * DIM + (g << 3);
    float4 v0 = *(const float4*)(src);
    float4 v1 = *(const float4*)(src + 4);
    f16x8 h = { (f16)(-1024.f*v0.x), (f16)(-1024.f*v0.y),
                (f16)(-1024.f*v0.z), (f16)(-1024.f*v0.w),
                (f16)(-1024.f*v1.x), (f16)(-1024.f*v1.y),
                (f16)(-1024.f*v1.z), (f16)(-1024.f*v1.w) };
    size_t byte = ((size_t)chunk << 14) + ((size_t)jl << 8) + (size_t)((g ^ (jl & 7)) << 4);
    *(f16x8*)((char*)bp + byte) = h;
}

// ---------------- fused: argmin-GEMM + gather + STE out + loss ----------------
// 512 blocks x 512 threads (8 waves: wr 2 x wc 4). Block: 128 rows x ALL codes.
// LDS ~70KB -> 2 blocks/CU -> 16 waves/CU = 4 waves/SIMD.
__global__ __launch_bounds__(512, 4) void vq_gemm(const float* __restrict__ batch,
                                                  const f16* __restrict__ bp,
                                                  const float* __restrict__ wgt,
                                                  float* __restrict__ out,
                                                  double* __restrict__ lsum,
                                                  unsigned int* __restrict__ cnt) {
    __shared__ __align__(16) char L[65536];          // A [0:32K] | B0 [32K:48K] | B1 [48K:64K]
    __shared__ unsigned long long key_lds[4][128];   // per-wc partial argmin keys
    __shared__ double dred[16];

    const int t = threadIdx.x;
    const int lane = t & 63, wv = t >> 6;
    const int m0 = blockIdx.x << 7;
    const int b = m0 >> 12, hw0 = m0 & 4095;

    // ---- issue B chunk0 -> B0 (flies during A staging) ----
    #pragma unroll
    for (int i = 0; i < 2; i++) {
        int o = (i << 13) + (wv << 10);
        load_lds16((const char*)bp + o + (lane << 4), L + 32768 + o);
    }

    // ---- stage A (once): batch[b][k][hw0+m] -> L[0:32K] as [m][k] swizzled ----
    #pragma unroll
    for (int i = 0; i < 2; i++) {
        int ktile = (t & 7) + (((t >> 8) + (i << 1)) << 3);   // 0..31
        int m4 = ((t >> 3) & 31) << 2;                        // 0..124
        const float* gp = batch + (((size_t)(b * DIM + (ktile << 2))) << 12) + hw0 + m4;
        float4 r0 = *(const float4*)(gp);
        float4 r1 = *(const float4*)(gp + 4096);
        float4 r2 = *(const float4*)(gp + 8192);
        float4 r3 = *(const float4*)(gp + 12288);
        int g = ktile >> 1, off8 = (ktile & 1) << 3;
        f16x4 h0 = { (f16)r0.x, (f16)r1.x, (f16)r2.x, (f16)r3.x };
        f16x4 h1 = { (f16)r0.y, (f16)r1.y, (f16)r2.y, (f16)r3.y };
        f16x4 h2 = { (f16)r0.z, (f16)r1.z, (f16)r2.z, (f16)r3.z };
        f16x4 h3 = { (f16)r0.w, (f16)r1.w, (f16)r2.w, (f16)r3.w };
        int m = m4;
        *(f16x4*)(L + (m << 8) + ((g ^ (m & 7)) << 4) + off8) = h0; m++;
        *(f16x4*)(L + (m << 8) + ((g ^ (m & 7)) << 4) + off8) = h1; m++;
        *(f16x4*)(L + (m << 8) + ((g ^ (m & 7)) << 4) + off8) = h2; m++;
        *(f16x4*)(L + (m << 8) + ((g ^ (m & 7)) << 4) + off8) = h3;
    }
    __syncthreads();   // A + B0 resident

    // ---- hoist A fragments to registers ----
    const int lr = lane & 15, lk = lane >> 4;
    const int wr = wv >> 2, wc = wv & 3;
    f16x8 af[4][4];                                // [mi][ks]
    #pragma unroll
    for (int mi = 0; mi < 4; mi++)
        #pragma unroll
        for (int ks = 0; ks < 4; ks++) {
            int m = (wr << 6) + (mi << 4) + lr;
            int g = (ks << 2) + lk;
            af[mi][ks] = *(const f16x8*)(L + (m << 8) + ((g ^ (m & 7)) << 4));
        }

    float bestS[4][4];
    int   bestI[4][4];
    #pragma unroll
    for (int mi = 0; mi < 4; mi++)
        #pragma unroll
        for (int r = 0; r < 4; r++) { bestS[mi][r] = 3.4e38f; bestI[mi][r] = 0; }

    const f32x4 zf = (f32x4){0.f, 0.f, 0.f, 0.f};
    const int jrow = (wc << 4) + lr;                        // B row this wave reads

    // ---- main loop over 40 code chunks, 2-phase dbuf ----
    for (int c = 0; c < NCH; c++) {
        __syncthreads();   // buf(c) resident (vmcnt drained at barrier); prev reads done
        if (c + 1 < NCH) {
            const char* src = (const char*)bp + ((size_t)(c + 1) << 14);
            char* dst = L + 32768 + (((c + 1) & 1) << 14);
            #pragma unroll
            for (int i = 0; i < 2; i++) {
                int o = (i << 13) + (wv << 10);
                load_lds16(src + o + (lane << 4), dst + o);
            }
        }
        const char* Bc = L + 32768 + ((c & 1) << 14);

        f16x8 bf = *(const f16x8*)(Bc + (jrow << 8) + ((lk ^ (jrow & 7)) << 4)); // ks=0
        f32x4 acc[4];
        #pragma unroll
        for (int mi = 0; mi < 4; mi++)
            acc[mi] = __builtin_amdgcn_mfma_f32_16x16x32_f16(af[mi][0], bf, zf, 0, 0, 0);
        #pragma unroll
        for (int ks = 1; ks < 4; ks++) {
            int g = (ks << 2) + lk;
            bf = *(const f16x8*)(Bc + (jrow << 8) + ((g ^ (jrow & 7)) << 4));
            #pragma unroll
            for (int mi = 0; mi < 4; mi++)
                acc[mi] = __builtin_amdgcn_mfma_f32_16x16x32_f16(af[mi][ks], bf, acc[mi], 0, 0, 0);
        }

        // running argmin (codes ascend with c -> strict < keeps lowest)
        int code = (c << 6) + jrow;
        #pragma unroll
        for (int mi = 0; mi < 4; mi++)
            #pragma unroll
            for (int r = 0; r < 4; r++) {
                float s = acc[mi][r];
                if (s < bestS[mi][r]) { bestS[mi][r] = s; bestI[mi][r] = code; }
            }
    }

    // ---- cross-lane argmin over the 16 codes (lr dim), packed u64 ----
    #pragma unroll
    for (int mi = 0; mi < 4; mi++)
        #pragma unroll
        for (int r = 0; r < 4; r++) {
            unsigned long long key =
                ((unsigned long long)ford(bestS[mi][r]) << 32) | (unsigned)bestI[mi][r];
            #pragma unroll
            for (int mask = 1; mask <= 8; mask <<= 1) {
                unsigned long long o = __shfl_xor(key, mask, 64);
                if (o < key) key = o;
            }
            if (lr == 0)
                key_lds[wc][(wr << 6) + (mi << 4) + (lk << 2) + r] = key;
        }
    __syncthreads();

    // ---- fused finalize: 8 waves; wave = 64 rows x 32 channels ----
    {
        const int row = ((wv & 1) << 6) + lane;
        const int cq  = wv >> 1;                   // 0..3 -> channels [cq*32, +32)
        unsigned long long k0 = key_lds[0][row], k1 = key_lds[1][row];
        unsigned long long k2 = key_lds[2][row], k3 = key_lds[3][row];
        unsigned long long ka = (k0 < k1) ? k0 : k1;
        unsigned long long kb = (k2 < k3) ? k2 : k3;
        const int idx = (int)(((ka < kb) ? ka : kb) & 0xFFFFFFFFu);

        const float* zp = batch + (((size_t)(b * DIM + (cq << 5))) << 12) + hw0 + row;
        float*       op = out   + (((size_t)(b * DIM + (cq << 5))) << 12) + hw0 + row;
        const float* wp = wgt + (size_t)idx * DIM + (cq << 5);

        double a12 = 0.0, a3 = 0.0;
        #pragma unroll 4
        for (int i4 = 0; i4 < 8; i4++) {
            float4 w4 = *(const float4*)(wp + (i4 << 2));
            #pragma unroll
            for (int k = 0; k < 4; k++) {
                int i = (i4 << 2) + k;
                float zv = zp[((size_t)i) << 12];
                float zw = (k == 0) ? w4.x : (k == 1) ? w4.y : (k == 2) ? w4.z : w4.w;
                float d  = zw - zv;                 // ref: z_q - z (fp32 round)
                float ov = zv + d;                  // ref STE forward
                op[((size_t)i) << 12] = ov;
                a12 += (double)(d * d);
                float d3 = zv - ov;                 // ref: batch - out
                a3  += (double)(d3 * d3);
            }
        }
        #pragma unroll
        for (int off = 32; off; off >>= 1) {
            a12 += __shfl_down(a12, off, 64);
            a3  += __shfl_down(a3,  off, 64);
        }
        if (lane == 0) { dred[wv * 2] = a12; dred[wv * 2 + 1] = a3; }
    }
    __syncthreads();

    // ---- per-block loss atomics + last-block finalizes the scalar ----
    if (t == 0) {
        double a = 0.0, c3 = 0.0;
        #pragma unroll
        for (int w2 = 0; w2 < 8; w2++) { a += dred[w2 * 2]; c3 += dred[w2 * 2 + 1]; }
        atomicAdd(&lsum[0], a);
        atomicAdd(&lsum[1], c3);
        __threadfence();
        unsigned int old = atomicAdd(cnt, 1u);
        if (old == 511u) {
            double sa = atomicAdd(&lsum[0], 0.0);   // device-scope read-back
            double sc = atomicAdd(&lsum[1], 0.0);
            out[8388608] = (float)((2.0 * sa + 50.0 * sc) / 8388608.0);
        }
    }
}

extern "C" void kernel_launch(void* const* d_in, const int* in_sizes, int n_in,
                              void* d_out, int out_size, void* d_ws, size_t ws_size,
                              hipStream_t stream) {
    const float* batch = (const float*)d_in[0];   // [16,128,64,64]
    const float* wgt   = (const float*)d_in[1];   // [2560,128]
    float* out = (float*)d_out;                   // 8388608 + 1 (loss)

    double*       lsum = (double*)d_ws;                       // 2 doubles @ 0
    unsigned int* cnt  = (unsigned int*)((char*)d_ws + 16);   // counter @ 16
    f16*          bp   = (f16*)((char*)d_ws + 16384);         // 640 KB swizzled codebook

    hipMemsetAsync(d_ws, 0, 32, stream);
    prep_code<<<(NUM * 16 + 255) / 256, 256, 0, stream>>>(wgt, bp);
    vq_gemm<<<NTOT / 128, 512, 0, stream>>>(batch, bp, wgt, out, lsum, cnt);
}